// Round 6
// baseline (671.282 us; speedup 1.0000x reference)
//
#include <hip/hip_runtime.h>

// MultiFeatureMOE: F=4, E=8, B=4096, D=512, H=1024, O=512.
// Round 6: 512-thread blocks (8 waves x 64x32 wave-tile) -> acc 32 regs/thread,
// ~24 resident waves/CU (vs ~12 at 4x4 acc). Register-packed epilogues now write
// 64B-aligned contiguous chunks. gemm2: 2 experts/block K=2048, bf16 partials.

#define F_ 4
#define E_ 8
#define B_ 4096
#define D_ 512
#define H_ 1024
#define O_ 512

typedef unsigned short ushort_t;
typedef __bf16 bf16x8 __attribute__((ext_vector_type(8)));
typedef float f32x4 __attribute__((ext_vector_type(4)));
typedef unsigned short ushort8_t __attribute__((ext_vector_type(8)));

__device__ inline ushort_t f2bf(float f) {
  union { float f; unsigned u; } v; v.f = f;
  unsigned r = v.u + 0x7FFFu + ((v.u >> 16) & 1u);  // RNE
  return (ushort_t)(r >> 16);
}
__device__ inline float bf2f(ushort_t u) {
  union { unsigned u; float f; } v; v.u = ((unsigned)u) << 16;
  return v.f;
}

__device__ inline void async16(const void* g, void* l) {
  __builtin_amdgcn_global_load_lds(
      (const __attribute__((address_space(1))) unsigned int*)g,
      (__attribute__((address_space(3))) unsigned int*)l, 16, 0, 0);
}

// ---------------- elementwise cast: features fp32 -> bf16 ----------------
__global__ void cast_feat_kernel(const float* __restrict__ in, ushort_t* __restrict__ out) {
  const int i = blockIdx.x * 256 + threadIdx.x;
  const float4 v = ((const float4*)in)[i];
  ushort4 o;
  o.x = f2bf(v.x); o.y = f2bf(v.y); o.z = f2bf(v.z); o.w = f2bf(v.w);
  ((ushort4*)out)[i] = o;
}

// ------------- batched transpose+cast: [R][C] fp32 -> [C][R] bf16 -------------
__global__ void transpose_cast_kernel(const float* __restrict__ in, ushort_t* __restrict__ out,
                                      int R, int C) {
  __shared__ float tile[64][65];
  const size_t zoff = (size_t)blockIdx.z * R * C;
  in += zoff; out += zoff;
  const int tx = threadIdx.x & 63, ty = threadIdx.x >> 6;
  const int r0 = blockIdx.y * 64, c0 = blockIdx.x * 64;
#pragma unroll
  for (int i = 0; i < 16; ++i) {
    const int r = ty + i * 4;
    tile[r][tx] = in[(size_t)(r0 + r) * C + c0 + tx];
  }
  __syncthreads();
#pragma unroll
  for (int i = 0; i < 16; ++i) {
    const int c = ty + i * 4;
    out[(size_t)(c0 + c) * R + r0 + tx] = f2bf(tile[tx][c]);
  }
}

// ---------------- gate: g2[f,b,e] = softmax_e(feat.Wg + bg) / F ----------------
__global__ void gate_kernel(const float* __restrict__ features, const float* __restrict__ Wg,
                            const float* __restrict__ bg, float* __restrict__ g2) {
  const int fb = blockIdx.x;
  const int f = fb >> 12, b = fb & (B_ - 1);
  const int lane = threadIdx.x;
  const float* feat = features + ((size_t)f * B_ + b) * D_;
  const float* wg = Wg + (size_t)f * D_ * E_;
  float acc[E_] = {0.f, 0.f, 0.f, 0.f, 0.f, 0.f, 0.f, 0.f};
  for (int d = lane; d < D_; d += 64) {
    const float fv = feat[d];
    const float4 w0 = ((const float4*)(wg + d * E_))[0];
    const float4 w1 = ((const float4*)(wg + d * E_))[1];
    acc[0] += fv * w0.x; acc[1] += fv * w0.y; acc[2] += fv * w0.z; acc[3] += fv * w0.w;
    acc[4] += fv * w1.x; acc[5] += fv * w1.y; acc[6] += fv * w1.z; acc[7] += fv * w1.w;
  }
#pragma unroll
  for (int off = 32; off >= 1; off >>= 1)
#pragma unroll
    for (int e = 0; e < E_; ++e) acc[e] += __shfl_xor(acc[e], off, 64);
  float lg[E_], mx = -1e30f;
#pragma unroll
  for (int e = 0; e < E_; ++e) { lg[e] = acc[e] + bg[f * E_ + e]; mx = fmaxf(mx, lg[e]); }
  float s = 0.f;
#pragma unroll
  for (int e = 0; e < E_; ++e) { lg[e] = __expf(lg[e] - mx); s += lg[e]; }
  const float inv = 1.f / (s * (float)F_);
  if (lane < E_) g2[((size_t)f * B_ + b) * E_ + lane] = lg[lane] * inv;
}

// ---------------- GEMM1: Hf[e][m][n] = bf16(g2 * relu(feat @ W1t_e + b1_e)) ----------------
// 512 threads, 8 waves, wave-tile 64x32. Swapped-operand MFMA:
// acc[i][j]: m = wm*64+i*16+lr, n = wn*32+j*16+q*4+{0..3}.
__global__ __launch_bounds__(512, 6) void gemm1_kernel(
    const ushort_t* __restrict__ A, const ushort_t* __restrict__ Bt,
    const float* __restrict__ b1, const float* __restrict__ g2,
    ushort_t* __restrict__ Hf) {
  __shared__ ushort_t As[128 * 32];
  __shared__ ushort_t Bs[128 * 32];
  const int id = blockIdx.x;
  const int e = id & 7;
  const int s = id >> 3;
  const int n0 = (s & 7) * 128;   // h
  const int m0 = (s >> 3) * 128;  // b
  const ushort_t* Bp = Bt + (size_t)e * H_ * D_;

  const int t = threadIdx.x, lane = t & 63, w = t >> 6;
  const int wm = w & 1, wn = w >> 1;   // wn in 0..3
  const int lr = lane & 15, q = lane >> 4;
  const int pc = q ^ ((lr >> 1) & 3);

  const int r0 = t >> 2;                       // 0..127
  const int g = (t & 3) ^ ((r0 >> 1) & 3);     // swizzled global chunk
  const char* aSrc = (const char*)A + (size_t)(m0 + r0) * (D_ * 2) + g * 16;
  const char* bSrc = (const char*)Bp + (size_t)(n0 + r0) * (D_ * 2) + g * 16;
  ushort_t* aDst = &As[t * 8];
  ushort_t* bDst = &Bs[t * 8];

  f32x4 acc[4][2];
#pragma unroll
  for (int i = 0; i < 4; ++i)
#pragma unroll
    for (int j = 0; j < 2; ++j) acc[i][j] = (f32x4){0.f, 0.f, 0.f, 0.f};

  for (int ks = 0; ks < D_ / 32; ++ks) {
    async16(aSrc, aDst);
    async16(bSrc, bDst);
    aSrc += 64; bSrc += 64;
    __syncthreads();
    bf16x8 af[4], bfr[2];
#pragma unroll
    for (int i = 0; i < 4; ++i)
      af[i] = *(const bf16x8*)&As[(wm * 64 + i * 16 + lr) * 32 + pc * 8];
#pragma unroll
    for (int j = 0; j < 2; ++j)
      bfr[j] = *(const bf16x8*)&Bs[(wn * 32 + j * 16 + lr) * 32 + pc * 8];
#pragma unroll
    for (int i = 0; i < 4; ++i)
#pragma unroll
      for (int j = 0; j < 2; ++j)
        acc[i][j] = __builtin_amdgcn_mfma_f32_16x16x32_bf16(bfr[j], af[i], acc[i][j], 0, 0, 0);
    __syncthreads();
  }

  // register epilogue: 64B-contiguous aligned chunks per row across q,j
  const float* b1e = b1 + (size_t)e * H_;
#pragma unroll
  for (int i = 0; i < 4; ++i) {
    const int m = m0 + wm * 64 + i * 16 + lr;
    const float gv = g2[m * E_ + e];
    ushort_t* dstRow = Hf + ((size_t)e * B_ + m) * H_ + n0 + wn * 32 + q * 4;
#pragma unroll
    for (int j = 0; j < 2; ++j) {
      const int n = n0 + wn * 32 + j * 16 + q * 4;
      const float4 bb = *(const float4*)&b1e[n];
      ushort4 o;
      o.x = f2bf(fmaxf(acc[i][j][0] + bb.x, 0.f) * gv);
      o.y = f2bf(fmaxf(acc[i][j][1] + bb.y, 0.f) * gv);
      o.z = f2bf(fmaxf(acc[i][j][2] + bb.z, 0.f) * gv);
      o.w = f2bf(fmaxf(acc[i][j][3] + bb.w, 0.f) * gv);
      *(ushort4*)(dstRow + j * 16) = o;
    }
  }
}

// ---------------- GEMM2: part[grp] = sum_{e in grp} Hf_e @ W2t_e + g*b2 (bf16) ----------------
__global__ __launch_bounds__(512, 6) void gemm2_kernel(
    const ushort_t* __restrict__ Hf, const ushort_t* __restrict__ Bt,
    const float* __restrict__ b2, const float* __restrict__ g2,
    ushort_t* __restrict__ part) {
  __shared__ ushort_t As[128 * 32];
  __shared__ ushort_t Bs[128 * 32];
  const int id = blockIdx.x;
  const int grp = id & 3;
  const int s = id >> 2;
  const int n0 = (s & 3) * 128;   // o
  const int m0 = (s >> 2) * 128;  // b
  const int e0 = grp * 2;

  const int t = threadIdx.x, lane = t & 63, w = t >> 6;
  const int wm = w & 1, wn = w >> 1;
  const int lr = lane & 15, q = lane >> 4;
  const int pc = q ^ ((lr >> 1) & 3);

  const int r0 = t >> 2;
  const int g = (t & 3) ^ ((r0 >> 1) & 3);
  ushort_t* aDst = &As[t * 8];
  ushort_t* bDst = &Bs[t * 8];

  f32x4 acc[4][2];
#pragma unroll
  for (int i = 0; i < 4; ++i)
#pragma unroll
    for (int j = 0; j < 2; ++j) acc[i][j] = (f32x4){0.f, 0.f, 0.f, 0.f};

  for (int h = 0; h < 2; ++h) {
    const int e = e0 + h;
    const char* aSrc = (const char*)(Hf + (size_t)e * B_ * H_) + (size_t)(m0 + r0) * (H_ * 2) + g * 16;
    const char* bSrc = (const char*)(Bt + (size_t)e * O_ * H_) + (size_t)(n0 + r0) * (H_ * 2) + g * 16;
    for (int ks = 0; ks < H_ / 32; ++ks) {
      async16(aSrc, aDst);
      async16(bSrc, bDst);
      aSrc += 64; bSrc += 64;
      __syncthreads();
      bf16x8 af[4], bfr[2];
#pragma unroll
      for (int i = 0; i < 4; ++i)
        af[i] = *(const bf16x8*)&As[(wm * 64 + i * 16 + lr) * 32 + pc * 8];
#pragma unroll
      for (int j = 0; j < 2; ++j)
        bfr[j] = *(const bf16x8*)&Bs[(wn * 32 + j * 16 + lr) * 32 + pc * 8];
#pragma unroll
      for (int i = 0; i < 4; ++i)
#pragma unroll
        for (int j = 0; j < 2; ++j)
          acc[i][j] = __builtin_amdgcn_mfma_f32_16x16x32_bf16(bfr[j], af[i], acc[i][j], 0, 0, 0);
      __syncthreads();
    }
  }

  const float* b2e0 = b2 + (size_t)e0 * O_;
  const float* b2e1 = b2e0 + O_;
#pragma unroll
  for (int i = 0; i < 4; ++i) {
    const int m = m0 + wm * 64 + i * 16 + lr;
    const float gv0 = g2[m * E_ + e0];
    const float gv1 = g2[m * E_ + e0 + 1];
    ushort_t* dstRow = part + (size_t)grp * (B_ * O_) + (size_t)m * O_ + n0 + wn * 32 + q * 4;
#pragma unroll
    for (int j = 0; j < 2; ++j) {
      const int n = n0 + wn * 32 + j * 16 + q * 4;
      const float4 c0 = *(const float4*)&b2e0[n];
      const float4 c1 = *(const float4*)&b2e1[n];
      ushort4 o;
      o.x = f2bf(acc[i][j][0] + gv0 * c0.x + gv1 * c1.x);
      o.y = f2bf(acc[i][j][1] + gv0 * c0.y + gv1 * c1.y);
      o.z = f2bf(acc[i][j][2] + gv0 * c0.z + gv1 * c1.z);
      o.w = f2bf(acc[i][j][3] + gv0 * c0.w + gv1 * c1.w);
      *(ushort4*)(dstRow + j * 16) = o;
    }
  }
}

// ---------------- final reduce: out = sum over 16 bf16 slabs ----------------
__global__ void reduce_kernel(const ushort_t* __restrict__ part, float* __restrict__ out) {
  const size_t p = ((size_t)blockIdx.x * 256 + threadIdx.x) * 8;
  float s[8] = {0.f, 0.f, 0.f, 0.f, 0.f, 0.f, 0.f, 0.f};
#pragma unroll
  for (int k = 0; k < F_ * 4; ++k) {
    const ushort8_t u = *(const ushort8_t*)&part[(size_t)k * (B_ * O_) + p];
#pragma unroll
    for (int j = 0; j < 8; ++j) s[j] += bf2f(u[j]);
  }
  float4 o0 = {s[0], s[1], s[2], s[3]}, o1 = {s[4], s[5], s[6], s[7]};
  *(float4*)&out[p] = o0;
  *(float4*)&out[p + 4] = o1;
}

extern "C" void kernel_launch(void* const* d_in, const int* in_sizes, int n_in,
                              void* d_out, int out_size, void* d_ws, size_t ws_size,
                              hipStream_t stream) {
  const float* features = (const float*)d_in[0];
  const float* W1 = (const float*)d_in[1];
  const float* b1 = (const float*)d_in[2];
  const float* W2 = (const float*)d_in[3];
  const float* b2 = (const float*)d_in[4];
  const float* Wg = (const float*)d_in[5];
  const float* bg = (const float*)d_in[6];
  float* out = (float*)d_out;

  char* ws = (char*)d_ws;
  ushort_t* featbf = (ushort_t*)ws;                       // 16 MB   [F][B][D]
  ushort_t* w1t    = (ushort_t*)(ws + 16777216);          // 32 MB   [F][E][H][D]
  ushort_t* w2t    = (ushort_t*)(ws + 50331648);          // 32 MB   [F][E][O][H]
  float*    g2     = (float*)(ws + 83886080);             // 0.5 MB  [F][B][E]
  ushort_t* Hf     = (ushort_t*)(ws + 84410368);          // 64 MB   [E][B][H], reused per f
  ushort_t* part   = (ushort_t*)(ws + 151519232);         // 64 MB   [F][4][B][O] bf16

  cast_feat_kernel<<<F_ * B_ * D_ / 1024, 256, 0, stream>>>(features, featbf);
  transpose_cast_kernel<<<dim3(H_ / 64, D_ / 64, F_ * E_), 256, 0, stream>>>(W1, w1t, D_, H_);
  transpose_cast_kernel<<<dim3(O_ / 64, H_ / 64, F_ * E_), 256, 0, stream>>>(W2, w2t, H_, O_);
  gate_kernel<<<F_ * B_, 64, 0, stream>>>(features, Wg, bg, g2);

  for (int f = 0; f < F_; ++f) {
    gemm1_kernel<<<(B_ / 128) * (H_ / 128) * E_, 512, 0, stream>>>(
        featbf + (size_t)f * B_ * D_,
        w1t + (size_t)f * E_ * H_ * D_,
        b1 + (size_t)f * E_ * H_,
        g2 + (size_t)f * B_ * E_,
        Hf);
    gemm2_kernel<<<(B_ / 128) * (O_ / 128) * 4, 512, 0, stream>>>(
        Hf,
        w2t + (size_t)f * E_ * O_ * H_,
        b2 + (size_t)f * E_ * O_,
        g2 + (size_t)f * B_ * E_,
        part + (size_t)f * 4 * B_ * O_);
  }
  reduce_kernel<<<B_ * O_ / 8 / 256, 256, 0, stream>>>(part, out);
}

// Round 7
// 640.532 us; speedup vs baseline: 1.0480x; 1.0480x over previous
//
#include <hip/hip_runtime.h>

// MultiFeatureMOE: F=4, E=8, B=4096, D=512, H=1024, O=512.
// Round 7: BK=64 K-loop (32 MFMA/wave per barrier, half the barriers), single
// 34816B LDS buffer reused for staging + coalesced epilogue, merged-f dispatches
// (ws-guarded: Hf[F] 256MB -> 6 launches; else per-f fallback, same kernels).

#define F_ 4
#define E_ 8
#define B_ 4096
#define D_ 512
#define H_ 1024
#define O_ 512

typedef unsigned short ushort_t;
typedef __bf16 bf16x8 __attribute__((ext_vector_type(8)));
typedef float f32x4 __attribute__((ext_vector_type(4)));
typedef unsigned short ushort8_t __attribute__((ext_vector_type(8)));

__device__ inline ushort_t f2bf(float f) {
  union { float f; unsigned u; } v; v.f = f;
  unsigned r = v.u + 0x7FFFu + ((v.u >> 16) & 1u);  // RNE
  return (ushort_t)(r >> 16);
}
__device__ inline float bf2f(ushort_t u) {
  union { unsigned u; float f; } v; v.u = ((unsigned)u) << 16;
  return v.f;
}

__device__ inline void async16(const void* g, void* l) {
  __builtin_amdgcn_global_load_lds(
      (const __attribute__((address_space(1))) unsigned int*)g,
      (__attribute__((address_space(3))) unsigned int*)l, 16, 0, 0);
}

// ---------------- prep: gate softmax (fp32) + feature bf16 cast, fused ----------------
__global__ void prep_kernel(const float* __restrict__ features, const float* __restrict__ Wg,
                            const float* __restrict__ bg, float* __restrict__ g2,
                            ushort_t* __restrict__ featbf) {
  const int fb = blockIdx.x;
  const int f = fb >> 12, b = fb & (B_ - 1);
  const int lane = threadIdx.x;
  const float* feat = features + ((size_t)f * B_ + b) * D_;
  const float* wg = Wg + (size_t)f * D_ * E_;
  const int d0 = lane * 8;
  float ff[8];
  *(float4*)&ff[0] = *(const float4*)&feat[d0];
  *(float4*)&ff[4] = *(const float4*)&feat[d0 + 4];
  ushort8_t u;
#pragma unroll
  for (int k = 0; k < 8; ++k) u[k] = f2bf(ff[k]);
  *(ushort8_t*)&featbf[((size_t)f * B_ + b) * D_ + d0] = u;

  float acc[E_] = {0.f, 0.f, 0.f, 0.f, 0.f, 0.f, 0.f, 0.f};
#pragma unroll
  for (int k = 0; k < 8; ++k) {
    const float fv = ff[k];
    const float4 w0 = ((const float4*)(wg + (size_t)(d0 + k) * E_))[0];
    const float4 w1 = ((const float4*)(wg + (size_t)(d0 + k) * E_))[1];
    acc[0] += fv * w0.x; acc[1] += fv * w0.y; acc[2] += fv * w0.z; acc[3] += fv * w0.w;
    acc[4] += fv * w1.x; acc[5] += fv * w1.y; acc[6] += fv * w1.z; acc[7] += fv * w1.w;
  }
#pragma unroll
  for (int off = 32; off >= 1; off >>= 1)
#pragma unroll
    for (int e = 0; e < E_; ++e) acc[e] += __shfl_xor(acc[e], off, 64);
  float lg[E_], mx = -1e30f;
#pragma unroll
  for (int e = 0; e < E_; ++e) { lg[e] = acc[e] + bg[f * E_ + e]; mx = fmaxf(mx, lg[e]); }
  float s = 0.f;
#pragma unroll
  for (int e = 0; e < E_; ++e) { lg[e] = __expf(lg[e] - mx); s += lg[e]; }
  const float inv = 1.f / (s * (float)F_);
  if (lane < E_) g2[((size_t)f * B_ + b) * E_ + lane] = lg[lane] * inv;
}

// ------------- batched transpose+cast: [R][C] fp32 -> [C][R] bf16 -------------
__global__ void transpose_cast_kernel(const float* __restrict__ in, ushort_t* __restrict__ out,
                                      int R, int C) {
  __shared__ float tile[64][65];
  const size_t zoff = (size_t)blockIdx.z * R * C;
  in += zoff; out += zoff;
  const int tx = threadIdx.x & 63, ty = threadIdx.x >> 6;
  const int r0 = blockIdx.y * 64, c0 = blockIdx.x * 64;
#pragma unroll
  for (int i = 0; i < 16; ++i) {
    const int r = ty + i * 4;
    tile[r][tx] = in[(size_t)(r0 + r) * C + c0 + tx];
  }
  __syncthreads();
#pragma unroll
  for (int i = 0; i < 16; ++i) {
    const int c = ty + i * 4;
    out[(size_t)(c0 + c) * R + r0 + tx] = f2bf(tile[tx][c]);
  }
}

// ================= GEMM engines: 128x128 tile, BK=64, 256 thr, 4 waves =================
// LDS: single 34816B buffer. K-loop: As=buf[0..8191], Bs=buf[8192..16383]
// ([128 rows][64 k], 16B chunks XOR-swizzled: phys = logical ^ (row&7)).
// Epilogue reuses buf as [128][136] bf16 C-tile for coalesced stores.
// Swapped-operand MFMA: acc[i][j]: m = wm*64+i*16+lr, n = wn*64+j*16+q*4+{0..3}.

// ---------------- GEMM1: Hf[f][e][m][n] = bf16(g2 * relu(feat @ W1t + b1)) ----------------
__global__ __launch_bounds__(256, 3) void gemm1_kernel(
    const ushort_t* __restrict__ featbf, const ushort_t* __restrict__ w1t,
    const float* __restrict__ b1, const float* __restrict__ g2,
    ushort_t* __restrict__ Hf, int f0, size_t hfStride) {
  __shared__ __align__(16) ushort_t buf[128 * 136];  // 34816 B
  ushort_t* As = buf;
  ushort_t* Bs = buf + 8192;
  const int fy = blockIdx.y, f = f0 + fy;
  const int id = blockIdx.x;
  const int e = id & 7;
  const int s = id >> 3;
  const int n0 = (s & 7) * 128;   // h
  const int m0 = (s >> 3) * 128;  // b
  const ushort_t* A  = featbf + (size_t)f * B_ * D_;
  const ushort_t* Bp = w1t + ((size_t)f * E_ + e) * H_ * D_;
  const float* b1e = b1 + ((size_t)f * E_ + e) * H_;
  const float* g2f = g2 + (size_t)f * B_ * E_;
  ushort_t* HfF = Hf + (size_t)fy * hfStride + (size_t)e * B_ * H_;

  const int t = threadIdx.x, lane = t & 63, w = t >> 6;
  const int wm = w & 1, wn = w >> 1;
  const int lr = lane & 15, q = lane >> 4;

  // staging: thread t stages phys chunks {p*256+t}, p=0..3; logical chunk is p-invariant
  const int rr = t >> 3;                  // row within p-slab (0..31)
  const int lc = (t & 7) ^ (rr & 7);      // logical 16B chunk
  const char* aSrc = (const char*)A + (size_t)(m0 + rr) * (D_ * 2) + lc * 16;
  const char* bSrc = (const char*)Bp + (size_t)(n0 + rr) * (D_ * 2) + lc * 16;

  f32x4 acc[4][4];
#pragma unroll
  for (int i = 0; i < 4; ++i)
#pragma unroll
    for (int j = 0; j < 4; ++j) acc[i][j] = (f32x4){0.f, 0.f, 0.f, 0.f};

  for (int ks = 0; ks < D_ / 64; ++ks) {   // 8 steps
#pragma unroll
    for (int p = 0; p < 4; ++p) {
      async16(aSrc + (size_t)p * (32 * D_ * 2), &As[t * 8 + p * 2048]);
      async16(bSrc + (size_t)p * (32 * D_ * 2), &Bs[t * 8 + p * 2048]);
    }
    aSrc += 128; bSrc += 128;
    __syncthreads();
#pragma unroll
    for (int kh = 0; kh < 2; ++kh) {
      const int ca = (((kh << 2) | q) ^ (lr & 7)) * 8;
      bf16x8 af[4], bfr[4];
#pragma unroll
      for (int i = 0; i < 4; ++i)
        af[i] = *(const bf16x8*)&As[(wm * 64 + i * 16 + lr) * 64 + ca];
#pragma unroll
      for (int j = 0; j < 4; ++j)
        bfr[j] = *(const bf16x8*)&Bs[(wn * 64 + j * 16 + lr) * 64 + ca];
#pragma unroll
      for (int i = 0; i < 4; ++i)
#pragma unroll
        for (int j = 0; j < 4; ++j)
          acc[i][j] = __builtin_amdgcn_mfma_f32_16x16x32_bf16(bfr[j], af[i], acc[i][j], 0, 0, 0);
    }
    __syncthreads();
  }

  // epilogue: bias+relu+gate -> LDS [128][136] -> coalesced stores
#pragma unroll
  for (int i = 0; i < 4; ++i) {
    const int ml = wm * 64 + i * 16 + lr;
    const float gv = g2f[(m0 + ml) * E_ + e];
#pragma unroll
    for (int j = 0; j < 4; ++j) {
      const int nl = wn * 64 + j * 16 + q * 4;
      const float4 bb = *(const float4*)&b1e[n0 + nl];
      ushort4 o;
      o.x = f2bf(fmaxf(acc[i][j][0] + bb.x, 0.f) * gv);
      o.y = f2bf(fmaxf(acc[i][j][1] + bb.y, 0.f) * gv);
      o.z = f2bf(fmaxf(acc[i][j][2] + bb.z, 0.f) * gv);
      o.w = f2bf(fmaxf(acc[i][j][3] + bb.w, 0.f) * gv);
      *(ushort4*)&buf[ml * 136 + nl] = o;
    }
  }
  __syncthreads();
  const int row = t >> 1, half = t & 1;
  const ushort_t* src = &buf[row * 136 + half * 64];
  ushort_t* dst = HfF + (size_t)(m0 + row) * H_ + n0 + half * 64;
#pragma unroll
  for (int c = 0; c < 8; ++c)
    *(ushort8_t*)(dst + c * 8) = *(const ushort8_t*)(src + c * 8);
}

// ---------------- GEMM2: part[f][grp] = sum_{e in grp} Hf_e @ W2t_e + g*b2 (bf16) ----------------
__global__ __launch_bounds__(256, 3) void gemm2_kernel(
    const ushort_t* __restrict__ Hf, const ushort_t* __restrict__ w2t,
    const float* __restrict__ b2, const float* __restrict__ g2,
    ushort_t* __restrict__ part, int f0, size_t hfStride) {
  __shared__ __align__(16) ushort_t buf[128 * 136];
  ushort_t* As = buf;
  ushort_t* Bs = buf + 8192;
  const int fy = blockIdx.y, f = f0 + fy;
  const int id = blockIdx.x;
  const int grp = id & 3;
  const int s = id >> 2;
  const int n0 = (s & 3) * 128;   // o
  const int m0 = (s >> 2) * 128;  // b
  const int e0 = grp * 2;
  const float* g2f = g2 + (size_t)f * B_ * E_;

  const int t = threadIdx.x, lane = t & 63, w = t >> 6;
  const int wm = w & 1, wn = w >> 1;
  const int lr = lane & 15, q = lane >> 4;

  const int rr = t >> 3;
  const int lc = (t & 7) ^ (rr & 7);

  f32x4 acc[4][4];
#pragma unroll
  for (int i = 0; i < 4; ++i)
#pragma unroll
    for (int j = 0; j < 4; ++j) acc[i][j] = (f32x4){0.f, 0.f, 0.f, 0.f};

  for (int h = 0; h < 2; ++h) {
    const int e = e0 + h;
    const char* aSrc = (const char*)(Hf + (size_t)fy * hfStride + (size_t)e * B_ * H_) +
                       (size_t)(m0 + rr) * (H_ * 2) + lc * 16;
    const char* bSrc = (const char*)(w2t + ((size_t)f * E_ + e) * O_ * H_) +
                       (size_t)(n0 + rr) * (H_ * 2) + lc * 16;
    for (int ks = 0; ks < H_ / 64; ++ks) {   // 16 steps per expert
#pragma unroll
      for (int p = 0; p < 4; ++p) {
        async16(aSrc + (size_t)p * (32 * H_ * 2), &As[t * 8 + p * 2048]);
        async16(bSrc + (size_t)p * (32 * H_ * 2), &Bs[t * 8 + p * 2048]);
      }
      aSrc += 128; bSrc += 128;
      __syncthreads();
#pragma unroll
      for (int kh = 0; kh < 2; ++kh) {
        const int ca = (((kh << 2) | q) ^ (lr & 7)) * 8;
        bf16x8 af[4], bfr[4];
#pragma unroll
        for (int i = 0; i < 4; ++i)
          af[i] = *(const bf16x8*)&As[(wm * 64 + i * 16 + lr) * 64 + ca];
#pragma unroll
        for (int j = 0; j < 4; ++j)
          bfr[j] = *(const bf16x8*)&Bs[(wn * 64 + j * 16 + lr) * 64 + ca];
#pragma unroll
        for (int i = 0; i < 4; ++i)
#pragma unroll
          for (int j = 0; j < 4; ++j)
            acc[i][j] = __builtin_amdgcn_mfma_f32_16x16x32_bf16(bfr[j], af[i], acc[i][j], 0, 0, 0);
      }
      __syncthreads();
    }
  }

  const float* b2e0 = b2 + ((size_t)f * E_ + e0) * O_;
  const float* b2e1 = b2e0 + O_;
#pragma unroll
  for (int i = 0; i < 4; ++i) {
    const int ml = wm * 64 + i * 16 + lr;
    const float gv0 = g2f[(m0 + ml) * E_ + e0];
    const float gv1 = g2f[(m0 + ml) * E_ + e0 + 1];
#pragma unroll
    for (int j = 0; j < 4; ++j) {
      const int nl = wn * 64 + j * 16 + q * 4;
      const int n = n0 + nl;
      const float4 c0 = *(const float4*)&b2e0[n];
      const float4 c1 = *(const float4*)&b2e1[n];
      ushort4 o;
      o.x = f2bf(acc[i][j][0] + gv0 * c0.x + gv1 * c1.x);
      o.y = f2bf(acc[i][j][1] + gv0 * c0.y + gv1 * c1.y);
      o.z = f2bf(acc[i][j][2] + gv0 * c0.z + gv1 * c1.z);
      o.w = f2bf(acc[i][j][3] + gv0 * c0.w + gv1 * c1.w);
      *(ushort4*)&buf[ml * 136 + nl] = o;
    }
  }
  __syncthreads();
  const int row = t >> 1, half = t & 1;
  const ushort_t* src = &buf[row * 136 + half * 64];
  ushort_t* dst = part + (size_t)(f * 4 + grp) * (B_ * O_) + (size_t)(m0 + row) * O_ + n0 + half * 64;
#pragma unroll
  for (int c = 0; c < 8; ++c)
    *(ushort8_t*)(dst + c * 8) = *(const ushort8_t*)(src + c * 8);
}

// ---------------- final reduce: out = sum over 16 bf16 slabs ----------------
__global__ void reduce_kernel(const ushort_t* __restrict__ part, float* __restrict__ out) {
  const size_t p = ((size_t)blockIdx.x * 256 + threadIdx.x) * 8;
  float s[8] = {0.f, 0.f, 0.f, 0.f, 0.f, 0.f, 0.f, 0.f};
#pragma unroll
  for (int k = 0; k < F_ * 4; ++k) {
    const ushort8_t u = *(const ushort8_t*)&part[(size_t)k * (B_ * O_) + p];
#pragma unroll
    for (int j = 0; j < 8; ++j) s[j] += bf2f(u[j]);
  }
  float4 o0 = {s[0], s[1], s[2], s[3]}, o1 = {s[4], s[5], s[6], s[7]};
  *(float4*)&out[p] = o0;
  *(float4*)&out[p + 4] = o1;
}

extern "C" void kernel_launch(void* const* d_in, const int* in_sizes, int n_in,
                              void* d_out, int out_size, void* d_ws, size_t ws_size,
                              hipStream_t stream) {
  const float* features = (const float*)d_in[0];
  const float* W1 = (const float*)d_in[1];
  const float* b1 = (const float*)d_in[2];
  const float* W2 = (const float*)d_in[3];
  const float* b2 = (const float*)d_in[4];
  const float* Wg = (const float*)d_in[5];
  const float* bg = (const float*)d_in[6];
  float* out = (float*)d_out;

  char* ws = (char*)d_ws;
  ushort_t* featbf = (ushort_t*)ws;                       // 16 MB   [F][B][D]
  ushort_t* w1t    = (ushort_t*)(ws + 16777216);          // 32 MB   [F][E][H][D]
  ushort_t* w2t    = (ushort_t*)(ws + 50331648);          // 32 MB   [F][E][O][H]
  float*    g2     = (float*)(ws + 83886080);             // 0.5 MB  [F][B][E]
  ushort_t* Hf     = (ushort_t*)(ws + 84410368);          // 64 MB (per-f) or 256 MB (merged)
  const bool big = ws_size >= (size_t)419954688;          // merged path needs ~400.5 MB
  ushort_t* part   = big ? (ushort_t*)(ws + 352845824)    // 64 MB [F][4][B][O] bf16
                         : (ushort_t*)(ws + 151519232);

  prep_kernel<<<F_ * B_, 64, 0, stream>>>(features, Wg, bg, g2, featbf);
  transpose_cast_kernel<<<dim3(H_ / 64, D_ / 64, F_ * E_), 256, 0, stream>>>(W1, w1t, D_, H_);
  transpose_cast_kernel<<<dim3(O_ / 64, H_ / 64, F_ * E_), 256, 0, stream>>>(W2, w2t, H_, O_);

  if (big) {
    gemm1_kernel<<<dim3((B_ / 128) * (H_ / 128) * E_, F_), 256, 0, stream>>>(
        featbf, w1t, b1, g2, Hf, 0, (size_t)E_ * B_ * H_);
    gemm2_kernel<<<dim3((B_ / 128) * (O_ / 128) * 4, F_), 256, 0, stream>>>(
        Hf, w2t, b2, g2, part, 0, (size_t)E_ * B_ * H_);
  } else {
    for (int f = 0; f < F_; ++f) {
      gemm1_kernel<<<dim3((B_ / 128) * (H_ / 128) * E_, 1), 256, 0, stream>>>(
          featbf, w1t, b1, g2, Hf, f, 0);
      gemm2_kernel<<<dim3((B_ / 128) * (O_ / 128) * 4, 1), 256, 0, stream>>>(
          Hf, w2t, b2, g2, part, f, 0);
    }
  }
  reduce_kernel<<<B_ * O_ / 8 / 256, 256, 0, stream>>>(part, out);
}